// Round 3
// baseline (127.116 us; speedup 1.0000x reference)
//
#include <hip/hip_runtime.h>
#include <math.h>

#define T_STEPS 9
#define D_IN    512
#define HID     64
#define G4      256   // 4*HID
#define BPB     8     // batches per block
#define NCH     8     // K chunks of 64

typedef short  short8 __attribute__((ext_vector_type(8)));
typedef float  f32x4  __attribute__((ext_vector_type(4)));
typedef unsigned int uint;
typedef unsigned short ushort;

// ---------------------------------------------------------------------------
__device__ __forceinline__ ushort f2bf(float f) {
    uint u = __float_as_uint(f);
    u = (u + 0x7FFFu + ((u >> 16) & 1u)) >> 16;   // RNE
    return (ushort)u;
}
__device__ __forceinline__ float fsig(float x) {
    return 1.0f / (1.0f + __expf(-x));
}
__device__ __forceinline__ float ftanh(float x) {
    float t = __expf(-2.0f * fabsf(x));
    float r = (1.0f - t) / (1.0f + t);
    return copysignf(r, x);
}
// packed f32 pair -> one uint holding 2 bf16 (RNE; low16 = cvt(a))
__device__ __forceinline__ uint cvtpk(float a, float b) {
    uint r;
    asm("v_cvt_pk_bf16_f32 %0, %1, %2" : "=v"(r) : "v"(a), "v"(b));
    return r;
}

// ---------------------------------------------------------------------------
// Prepass: weights -> bf16 fragment layouts; coalesced reads AND coalesced
// 16B writes. WxT: [blk(64)][n(256)][j(8)], k = blk*8+j.
// WhT: [kq(8)][n(256)][j(8)].
__global__ __launch_bounds__(256)
void prep_w(const float* __restrict__ kern, ushort* __restrict__ wxT,
            ushort* __restrict__ whT)
{
    const int blk = blockIdx.x;           // 0..63 -> wxT, 64..71 -> whT
    const int n   = threadIdx.x;          // 0..255
    const int krow0 = (blk < 64) ? blk * 8 : 512 + (blk - 64) * 8;
    union { ushort us[8]; short8 v; } o;
    #pragma unroll
    for (int j = 0; j < 8; ++j)
        o.us[j] = f2bf(kern[(size_t)(krow0 + j) * G4 + n]);
    if (blk < 64) *(short8*)&wxT[((size_t)blk * 256 + n) * 8] = o.v;
    else          *(short8*)&whT[((size_t)(blk - 64) * 256 + n) * 8] = o.v;
}

// ---------------------------------------------------------------------------
// Fused LSTM, R11: bf16 reg-staged chunk pipeline.
//   Phase 1: 8 chunks of K=64. Per chunk, each thread loads 5 float4 of x
//   (coalesced; issued 3 chunks ahead), converts via v_cvt_pk_bf16_f32 and
//   ds_write_b64 into a bf16 chunk tile with R8's verified swizzle:
//   ushort addr = row*64 + ((oct ^ (row&7))*8) + half*4. Both the writes
//   (32 banks/cyc) and the ds_read_b128 fragment reads (8 lanes per 4-bank
//   group) are bank-conflict-free. Triple-buffered LDS (chunk m -> buf m%3),
//   bFb (Wx fragments) prefetched one chunk ahead (reg double-buffer).
//   NO manual vmcnt: all VM ops are C++ loads with true deps -> compiler
//   emits exact counted waits; nothing drains to 0. One lgkmcnt(0)+s_barrier
//   per chunk. Steady in-flight/wave: 2 stage batches (10KB) + 1 bFb (8KB).
//   Buffer safety (triple buf): write of chunk k+1 (iter k, pre-barrier-k)
//   targets buf (k+1)%3, disjoint from buf k%3 (concurrent readers of chunk
//   k, post-barrier-k) and buf (k-1)%3 (chunk k-1 readers pre-barrier-k);
//   previous content (chunk k-2) was consumed before barrier k-1.
//   Phase 2: R7/R10's verified parity recurrence, one raw barrier/step.
__global__ __launch_bounds__(256, 2)
void lstm_fused(const float* __restrict__ x, const ushort* __restrict__ wxT,
                const ushort* __restrict__ whT, const float* __restrict__ bias,
                float* __restrict__ out)
{
    __shared__ __align__(16) ushort sA[3][80 * 64];  // 3 x 10 KB bf16 chunks
    __shared__ __align__(16) ushort sH[1024];        // 2 KB [kq(8)][m(16)][j(8)]

    const int t = threadIdx.x;
    const int w = t >> 6, l = t & 63;
    const int lane15 = l & 15, quad = l >> 4;
    const int u = w * 16 + lane15;

    // ---- staging constants: thread t, segment j covers chunk-tile row
    // row = j*16 + (t>>4), k-quad sq = t&15 (4 f32 = 16B src, 8B bf16 dst).
    // Tile row = s*8+b -> x row b*9+s; rows 72-79 clamp to s=8 (garbage ok:
    // their C rows are never consumed).
    const float* xbase = x + (size_t)blockIdx.x * (72 * D_IN);
    const int sq = t & 15, ow = sq >> 1, hw = sq & 1;
    int src[5], wad[5];
    #pragma unroll
    for (int j = 0; j < 5; ++j) {
        int row = j * 16 + (t >> 4);
        int b_ = row & 7, s_ = row >> 3;
        if (s_ > 8) s_ = 8;
        src[j] = (b_ * 9 + s_) * 512 + sq * 4;
        wad[j] = row * 64 + ((ow ^ (row & 7)) << 3) + (hw << 2);  // ushorts
    }

    // ---- zero sH (h_0 = 0); visible to all waves after iter-0 barrier
    if (t < 128) {
        uint4 z = {0u, 0u, 0u, 0u};
        *(uint4*)&sH[t * 8] = z;
    }

    // ---- prologue: S0 -> svA, S1 -> svB, bFb chunk0 -> set0
    float4 svA[5], svB[5];
    #pragma unroll
    for (int j = 0; j < 5; ++j) svA[j] = *(const float4*)&xbase[src[j]];
    #pragma unroll
    for (int j = 0; j < 5; ++j) svB[j] = *(const float4*)&xbase[src[j] + 64];

    short8 bFb[2][2][4];
    #pragma unroll
    for (int kk = 0; kk < 2; ++kk)
        #pragma unroll
        for (int g = 0; g < 4; ++g)
            bFb[0][kk][g] = *(const short8*)
                &wxT[(size_t)((kk * 4 + quad) * 256 + g * 64 + u) * 8];

    // write chunk 0 (consumes svA), then refill svA with S2
    #pragma unroll
    for (int j = 0; j < 5; ++j) {
        uint2 p;
        p.x = cvtpk(svA[j].x, svA[j].y);
        p.y = cvtpk(svA[j].z, svA[j].w);
        *(uint2*)&sA[0][wad[j]] = p;
    }
    #pragma unroll
    for (int j = 0; j < 5; ++j) svA[j] = *(const float4*)&xbase[src[j] + 128];

    // =============  Phase 1: pipelined K-chunks  ===============
    f32x4 acc[5][4];
    #pragma unroll
    for (int i = 0; i < 5; ++i)
        #pragma unroll
        for (int g = 0; g < 4; ++g)
            acc[i][g] = (f32x4){0.f, 0.f, 0.f, 0.f};

    #pragma unroll
    for (int k = 0; k < NCH; ++k) {
        // (b) write chunk k+1 from reg set (k+1)&1
        if (k < NCH - 1) {
            #pragma unroll
            for (int j = 0; j < 5; ++j) {
                float4 v = ((k + 1) & 1) ? svB[j] : svA[j];
                uint2 p;
                p.x = cvtpk(v.x, v.y);
                p.y = cvtpk(v.z, v.w);
                *(uint2*)&sA[(k + 1) % 3][wad[j]] = p;
            }
        }
        // (c1) prefetch bFb for chunk k+1 into set (k+1)&1 (L2-resident)
        if (k < NCH - 1) {
            #pragma unroll
            for (int kk = 0; kk < 2; ++kk)
                #pragma unroll
                for (int g = 0; g < 4; ++g)
                    bFb[(k + 1) & 1][kk][g] = *(const short8*)
                        &wxT[(size_t)((((k + 1) * 2 + kk) * 4 + quad) * 256
                                      + g * 64 + u) * 8];
        }
        // (c2) issue stage loads for chunk k+3 into set (k+3)&1 = (k+1)&1
        //      (freed by (b) above); they stay in flight across the barrier
        if (k < NCH - 3) {
            #pragma unroll
            for (int j = 0; j < 5; ++j) {
                float4 v = *(const float4*)&xbase[src[j] + (k + 3) * 64];
                if ((k + 3) & 1) svB[j] = v; else svA[j] = v;
            }
        }
        // fence: own ds_writes drained; raw barrier (no vmcnt drain!)
        asm volatile("s_waitcnt lgkmcnt(0)" ::: "memory");
        __builtin_amdgcn_sched_barrier(0);
        __builtin_amdgcn_s_barrier();
        __builtin_amdgcn_sched_barrier(0);
        asm volatile("" ::: "memory");
        // (d) compute chunk k: 10x ds_read_b128 (conflict-free) + 40 MFMA
        #pragma unroll
        for (int kk = 0; kk < 2; ++kk) {
            #pragma unroll
            for (int i = 0; i < 5; ++i) {
                int row = i * 16 + lane15;
                short8 aF = *(const short8*)
                    &sA[k % 3][row * 64 + (((kk * 4 + quad) ^ (row & 7)) << 3)];
                #pragma unroll
                for (int g = 0; g < 4; ++g)
                    acc[i][g] = __builtin_amdgcn_mfma_f32_16x16x32_bf16(
                        aF, bFb[k & 1][kk][g], acc[i][g], 0, 0, 0);
            }
        }
    }

    // =======================  Phase 2: recurrence  ========================
    short8 whF[4][2];
    #pragma unroll
    for (int g = 0; g < 4; ++g)
        #pragma unroll
        for (int kh = 0; kh < 2; ++kh)
            whF[g][kh] = *(const short8*)
                &whT[(size_t)((kh * 4 + quad) * 256 + g * 64 + u) * 8];

    float bia[4];
    bia[0] = bias[u];
    bia[1] = bias[64 + u];
    bia[2] = bias[128 + u] + 1.0f;       // FORGET_BIAS folded
    bia[3] = bias[192 + u];

    float cst[4] = {0.f, 0.f, 0.f, 0.f};
    const int b0 = blockIdx.x * BPB;

    #pragma unroll                         // static acc[] indices
    for (int s = 0; s < T_STEPS; ++s) {
        const int  i = s >> 1;
        const int  p = s & 1;
        const bool active = ((quad >> 1) == p);   // quads {2p,2p+1} hold step s
        const int  bofs = (quad & 1) * 4;         // batch = bofs + r

        f32x4 g4[4];
        #pragma unroll
        for (int g = 0; g < 4; ++g)
            #pragma unroll
            for (int r = 0; r < 4; ++r)
                g4[g][r] = acc[i][g][r] + bia[g];

        // h_{s-1} fragments: active C rows (8p..8p+7) depend only on sH rows
        // holding h_{s-1}; the other half feeds inactive C rows only.
        short8 aF[2];
        #pragma unroll
        for (int kh = 0; kh < 2; ++kh)
            aF[kh] = *(const short8*)&sH[((kh * 4 + quad) * 16 + lane15) * 8];

        #pragma unroll
        for (int g = 0; g < 4; ++g)
            #pragma unroll
            for (int kh = 0; kh < 2; ++kh)
                g4[g] = __builtin_amdgcn_mfma_f32_16x16x32_bf16(
                    aF[kh], whF[g][kh], g4[g], 0, 0, 0);

        const int wrow = 8 * ((s + 1) & 1);   // rows for h_s = next parity
        #pragma unroll
        for (int r = 0; r < 4; ++r) {
            float cp = __shfl_xor(cst[r], 32);   // partner quad's c_{s-1}
            if (active) {
                float ii = fsig(g4[0][r]);
                float jj = ftanh(g4[1][r]);
                float ff = fsig(g4[2][r]);
                float oo = fsig(g4[3][r]);
                float c  = ff * cp + ii * jj;
                cst[r] = c;
                float h = oo * ftanh(c);
                int bb = bofs + r;
                out[((size_t)(b0 + bb) * T_STEPS + s) * HID + u] = h;
                sH[((u >> 3) * 16 + wrow + bb) * 8 + (u & 7)] = f2bf(h);
            }
        }
        // single barrier/step: own ds_writes drained (lgkm), out-stores NOT
        // drained (raw s_barrier, no vmcnt(0))
        asm volatile("s_waitcnt lgkmcnt(0)" ::: "memory");
        __builtin_amdgcn_sched_barrier(0);
        __builtin_amdgcn_s_barrier();
        __builtin_amdgcn_sched_barrier(0);
    }
}

// ---------------------------------------------------------------------------
extern "C" void kernel_launch(void* const* d_in, const int* in_sizes, int n_in,
                              void* d_out, int out_size, void* d_ws, size_t ws_size,
                              hipStream_t stream)
{
    const float* x    = (const float*)d_in[0];
    const float* kern = (const float*)d_in[1];
    const float* bias = (const float*)d_in[2];
    float* out = (float*)d_out;

    const int B = in_sizes[0] / (T_STEPS * D_IN);   // 4096

    ushort* wxT = (ushort*)d_ws;                    // 256 KB
    ushort* whT = (ushort*)((char*)d_ws + 262144);  // 32 KB

    prep_w<<<72, 256, 0, stream>>>(kern, wxT, whT);
    lstm_fused<<<B / BPB, 256, 0, stream>>>(x, wxT, whT, bias, out);
}